// Round 10
// baseline (168.007 us; speedup 1.0000x reference)
//
#include <hip/hip_runtime.h>
#include <hip/hip_bf16.h>

#define BATCH 8
#define CIN   64
#define COUT  64
#define HH    128
#define WW    128
#define HW    (HH * WW)
#define ALPHA 8.3f
#define TPX   64
#define XW    66

typedef __attribute__((ext_vector_type(8))) short short8;   // 8 bf16 = 4 VGPR
typedef __attribute__((ext_vector_type(4))) float f32x4;

// index (in shorts) into s_img[6][XW][64], XOR-swizzled in 8-short (16B) slots
__device__ __forceinline__ int img_idx(int r, int x, int c) {
    return (((r * XW + x) << 6) + c) ^ ((x & 7) << 3);
}

// pre-kernel: weight [o][c][k] f32 -> wt [k][o][c] bf16
__global__ __launch_bounds__(256)
void transpose_w(const float* __restrict__ w, __hip_bfloat16* __restrict__ wt) {
    int i = blockIdx.x * 256 + threadIdx.x;
    if (i >= 9 * 64 * 64) return;
    int c = i & 63;
    int o = (i >> 6) & 63;
    int tap = i >> 12;
    wt[i] = __float2bfloat16(w[(o * 64 + c) * 9 + tap]);
}

// 512 threads = 8 waves: waves 0-3 compute y-pair 0, waves 4-7 pair 1.
// LDS 61.5 KB -> 2 blocks/CU; (512,4) pins VGPR <= 128 so 2 blocks actually
// fit (16 waves/CU). Live-register estimate ~115 (bb liveness reduced to 8),
// so the cap should not spill. Spill detector: WRITE_SIZE must stay 32768 KB.
// (Round 4 lesson: a cap far below need (64 vs 120) caused 200 MB spill
// traffic; a cap ~110% of need is insurance.)
__global__ __launch_bounds__(512, 4)
void depthconv_fused(const float* __restrict__ image,
                     const float* __restrict__ depth,
                     const float* __restrict__ bias,
                     const short* __restrict__ wt,     // [9][64 o][64 c] bf16
                     float* __restrict__ out) {
    __shared__ short s_img[6 * XW * 64];      // 50688 B, rows y0-1..y0+4
    __shared__ float s_d[6][XW];              //  1584 B
    __shared__ float s_sim[4][9][TPX];        //  9216 B  (total 61488)

    const int tid = threadIdx.x;
    const int bid = blockIdx.x;
    const int yg = bid & 31;                  // 32 groups of 4 y-rows
    const int xt = (bid >> 5) & 1;
    const int b  = bid >> 6;
    const int x0 = xt * TPX;
    const int y0 = yg * 4;

    const int lane = tid & 63;
    const int wid  = tid >> 6;                // 0..7
    const int l15  = lane & 15;
    const int lq   = lane >> 4;
    const int og   = wid & 3;                 // o-group
    const int pr   = wid >> 2;                // y-pair 0/1
    const int o_base = og * 16;

    // ---- staging: wave = row slot ----
    if (wid < 6) {
        // interior x=1..64 of window row `wid`: fixed (x,row), loop channels
        const int sx  = 1 + lane;
        const int gy  = y0 - 1 + wid;
        const bool yok = (unsigned)gy < HH;
        const int gx  = x0 + lane;                      // in [0,127]
        const float* ip = &image[((b * CIN) * HH + (yok ? gy : 0)) * WW + gx];
        const int base = (wid * XW + sx) << 6;
        const int swz  = (sx & 7) << 3;
        #pragma unroll 16
        for (int c2 = 0; c2 < 32; ++c2) {
            float v0 = ip[0], v1 = ip[HW];
            if (!yok) { v0 = 0.f; v1 = 0.f; }
            ip += 2 * HW;
            __hip_bfloat162 pk = __float22bfloat162_rn(float2{v0, v1});
            *(__hip_bfloat162*)&s_img[base + ((2 * c2) ^ swz)] = pk;
        }
    } else if (wid == 6) {
        // edge columns x=0,65 for all 6 rows: threads 0..11 each do one (row,edge)
        if (lane < 12) {
            const int rr = lane >> 1, e = lane & 1;
            const int sx = e ? (XW - 1) : 0;
            const int gy = y0 - 1 + rr;
            const int gx = x0 - 1 + sx;
            const bool ok = (unsigned)gy < HH && (unsigned)gx < WW;
            const float* p = &image[((b * CIN) * HH + (ok ? gy : 0)) * WW + (ok ? gx : 0)];
            #pragma unroll 8
            for (int c2 = 0; c2 < 32; ++c2) {
                float v0 = p[0], v1 = p[HW];
                if (!ok) { v0 = 0.f; v1 = 0.f; }
                p += 2 * HW;
                __hip_bfloat162 pk = __float22bfloat162_rn(float2{v0, v1});
                *(__hip_bfloat162*)&s_img[img_idx(rr, sx, 2 * c2)] = pk;
            }
        }
    } else {
        // depth rows y0-1..y0+4
        for (int i = lane; i < 6 * XW; i += 64) {
            int rr = i / XW, x = i - rr * XW;
            int gy = y0 - 1 + rr, gx = x0 - 1 + x;
            float v = 0.f;
            if ((unsigned)gy < HH && (unsigned)gx < WW)
                v = depth[(b * HH + gy) * WW + gx];
            s_d[rr][x] = v;
        }
    }
    __syncthreads();

    // ---- sim for 4 output rows: exp(-a*|d - d_tap0|), tap0 = (-1,-1) ----
    for (int i = tid; i < 4 * 9 * TPX; i += 512) {
        int p  = i & 63;
        int t  = i >> 6;                                // 0..35
        int yy = t / 9, tap = t - yy * 9;
        int ri = tap / 3, dj = tap - ri * 3;
        float dt = s_d[yy + ri][p + dj];
        float dc = s_d[yy][p];
        s_sim[yy][tap][p] = __expf(-ALPHA * fabsf(dt - dc));
    }

    // ---- A-fragments (loaded post-staging so staging regs are dead) ----
    short8 wfrag[9][2];
    #pragma unroll
    for (int tap = 0; tap < 9; ++tap)
        #pragma unroll
        for (int h = 0; h < 2; ++h)
            wfrag[tap][h] = *(const short8*)&wt[(tap * 64 + o_base + l15) * 64 + h * 32 + lq * 8];

    float bias_v[4];
    #pragma unroll
    for (int r = 0; r < 4; ++r) bias_v[r] = bias[o_base + lq * 4 + r];

    __syncthreads();

    // ---- compute this wave's y-pair (rows y0+2pr, y0+2pr+1), window rows 2pr..2pr+3 ----
    #pragma unroll
    for (int nt = 0; nt < 4; ++nt) {
        const int xb = nt * 16 + l15;
        f32x4 a0 = f32x4{0.f, 0.f, 0.f, 0.f};
        f32x4 a1 = f32x4{0.f, 0.f, 0.f, 0.f};
        #pragma unroll
        for (int r = 0; r < 4; ++r) {
            const int rr = 2 * pr + r;
            #pragma unroll
            for (int dj = 0; dj < 3; ++dj) {
                // just-in-time B-frag loads: 8 live regs, not 24
                short8 b0 = *(const short8*)&s_img[img_idx(rr, xb + dj, lq * 8)];
                short8 b1 = *(const short8*)&s_img[img_idx(rr, xb + dj, 32 + lq * 8)];
                if (r < 3) {                           // feeds row y0+2pr
                    const int tap = 3 * r + dj;
                    f32x4 t0 = __builtin_amdgcn_mfma_f32_16x16x32_bf16(
                        wfrag[tap][0], b0, (f32x4){0.f, 0.f, 0.f, 0.f}, 0, 0, 0);
                    t0 = __builtin_amdgcn_mfma_f32_16x16x32_bf16(
                        wfrag[tap][1], b1, t0, 0, 0, 0);
                    const float sv = s_sim[2 * pr][tap][xb];
                    #pragma unroll
                    for (int e = 0; e < 4; ++e) a0[e] = fmaf(sv, t0[e], a0[e]);
                }
                if (r >= 1) {                          // feeds row y0+2pr+1
                    const int tap = 3 * (r - 1) + dj;
                    f32x4 t1 = __builtin_amdgcn_mfma_f32_16x16x32_bf16(
                        wfrag[tap][0], b0, (f32x4){0.f, 0.f, 0.f, 0.f}, 0, 0, 0);
                    t1 = __builtin_amdgcn_mfma_f32_16x16x32_bf16(
                        wfrag[tap][1], b1, t1, 0, 0, 0);
                    const float sv = s_sim[2 * pr + 1][tap][xb];
                    #pragma unroll
                    for (int e = 0; e < 4; ++e) a1[e] = fmaf(sv, t1[e], a1[e]);
                }
            }
        }
        const int px = x0 + xb;
        const int yb = y0 + 2 * pr;
        #pragma unroll
        for (int rr = 0; rr < 4; ++rr) {
            const int o = o_base + lq * 4 + rr;
            out[((b * COUT + o) * HH + yb) * WW + px]     = a0[rr] + bias_v[rr];
            out[((b * COUT + o) * HH + yb + 1) * WW + px] = a1[rr] + bias_v[rr];
        }
    }
}

extern "C" void kernel_launch(void* const* d_in, const int* in_sizes, int n_in,
                              void* d_out, int out_size, void* d_ws, size_t ws_size,
                              hipStream_t stream) {
    const float* image  = (const float*)d_in[0];
    const float* depth  = (const float*)d_in[1];
    const float* weight = (const float*)d_in[2];
    const float* bias   = (const float*)d_in[3];
    float* out = (float*)d_out;
    __hip_bfloat16* wt = (__hip_bfloat16*)d_ws;       // 9*64*64 bf16 = 73728 B

    transpose_w<<<(9 * 64 * 64 + 255) / 256, 256, 0, stream>>>(weight, wt);

    dim3 grid(BATCH * 2 * 32);                        // 512 blocks, 4 y-rows each
    depthconv_fused<<<grid, 512, 0, stream>>>(image, depth, bias,
                                              (const short*)wt, out);
}

// Round 11
// 108.590 us; speedup vs baseline: 1.5472x; 1.5472x over previous
//
#include <hip/hip_runtime.h>
#include <hip/hip_bf16.h>

#define BATCH 8
#define CIN   64
#define COUT  64
#define HH    128
#define WW    128
#define HW    (HH * WW)
#define ALPHA 8.3f
#define TPX   64
#define XW    66

typedef __attribute__((ext_vector_type(8))) short short8;   // 8 bf16 = 4 VGPR
typedef __attribute__((ext_vector_type(4))) float f32x4;

// index (in shorts) into s_img[6][XW][64], XOR-swizzled in 8-short (16B) slots
__device__ __forceinline__ int img_idx(int r, int x, int c) {
    return (((r * XW + x) << 6) + c) ^ ((x & 7) << 3);
}

// pre-kernel: weight [o][c][k] f32 -> wt [k][o][c] bf16
__global__ __launch_bounds__(256)
void transpose_w(const float* __restrict__ w, __hip_bfloat16* __restrict__ wt) {
    int i = blockIdx.x * 256 + threadIdx.x;
    if (i >= 9 * 64 * 64) return;
    int c = i & 63;
    int o = (i >> 6) & 63;
    int tap = i >> 12;
    wt[i] = __float2bfloat16(w[(o * 64 + c) * 9 + tap]);
}

// 512 threads = 8 waves: waves 0-3 compute y-pair 0, waves 4-7 pair 1.
// LDS 61.5 KB -> 2 blocks/CU = 16 waves/CU, which requires VGPR <= 128
// (waves/CU halve at 64/128/256). We get under 128 STRUCTURALLY: A-frags
// are JIT-loaded per (r,dj) (16 live VGPR) instead of a resident
// wfrag[9][2] (72 VGPR). NOTE: NEVER use __launch_bounds__ arg 2 -- both
// (256,4) [R4] and (512,4) [R10] forced VGPR=64 and caused ~150-200 MB of
// scratch spill traffic. Spill detector: WRITE_SIZE must stay 32768 KB.
__global__ __launch_bounds__(512)
void depthconv_fused(const float* __restrict__ image,
                     const float* __restrict__ depth,
                     const float* __restrict__ bias,
                     const short* __restrict__ wt,     // [9][64 o][64 c] bf16
                     float* __restrict__ out) {
    __shared__ short s_img[6 * XW * 64];      // 50688 B, rows y0-1..y0+4
    __shared__ float s_d[6][XW];              //  1584 B
    __shared__ float s_sim[4][9][TPX];        //  9216 B  (total 61488)

    const int tid = threadIdx.x;
    // XCD-aware bijective swizzle: 512 blocks, 8 XCDs -> XCD k owns batch k
    // (2 MB image slice fits the 4 MB per-XCD L2).
    const int bid = ((blockIdx.x & 7) << 6) | (blockIdx.x >> 3);
    const int yg = bid & 31;                  // 32 groups of 4 y-rows
    const int xt = (bid >> 5) & 1;
    const int b  = bid >> 6;
    const int x0 = xt * TPX;
    const int y0 = yg * 4;

    const int lane = tid & 63;
    const int wid  = tid >> 6;                // 0..7
    const int l15  = lane & 15;
    const int lq   = lane >> 4;
    const int og   = wid & 3;                 // o-group
    const int pr   = wid >> 2;                // y-pair 0/1
    const int o_base = og * 16;

    // ---- staging: wave = row slot ----
    if (wid < 6) {
        // interior x=1..64 of window row `wid`: fixed (x,row), loop channels
        const int sx  = 1 + lane;
        const int gy  = y0 - 1 + wid;
        const bool yok = (unsigned)gy < HH;
        const int gx  = x0 + lane;                      // in [0,127]
        const float* ip = &image[((b * CIN) * HH + (yok ? gy : 0)) * WW + gx];
        const int base = (wid * XW + sx) << 6;
        const int swz  = (sx & 7) << 3;
        #pragma unroll 16
        for (int c2 = 0; c2 < 32; ++c2) {
            float v0 = ip[0], v1 = ip[HW];
            if (!yok) { v0 = 0.f; v1 = 0.f; }
            ip += 2 * HW;
            __hip_bfloat162 pk = __float22bfloat162_rn(float2{v0, v1});
            *(__hip_bfloat162*)&s_img[base + ((2 * c2) ^ swz)] = pk;
        }
    } else if (wid == 6) {
        // edge columns x=0,65 for all 6 rows: threads 0..11 each do one (row,edge)
        if (lane < 12) {
            const int rr = lane >> 1, e = lane & 1;
            const int sx = e ? (XW - 1) : 0;
            const int gy = y0 - 1 + rr;
            const int gx = x0 - 1 + sx;
            const bool ok = (unsigned)gy < HH && (unsigned)gx < WW;
            const float* p = &image[((b * CIN) * HH + (ok ? gy : 0)) * WW + (ok ? gx : 0)];
            #pragma unroll 8
            for (int c2 = 0; c2 < 32; ++c2) {
                float v0 = p[0], v1 = p[HW];
                if (!ok) { v0 = 0.f; v1 = 0.f; }
                p += 2 * HW;
                __hip_bfloat162 pk = __float22bfloat162_rn(float2{v0, v1});
                *(__hip_bfloat162*)&s_img[img_idx(rr, sx, 2 * c2)] = pk;
            }
        }
    } else {
        // depth rows y0-1..y0+4
        for (int i = lane; i < 6 * XW; i += 64) {
            int rr = i / XW, x = i - rr * XW;
            int gy = y0 - 1 + rr, gx = x0 - 1 + x;
            float v = 0.f;
            if ((unsigned)gy < HH && (unsigned)gx < WW)
                v = depth[(b * HH + gy) * WW + gx];
            s_d[rr][x] = v;
        }
    }
    __syncthreads();

    // ---- sim for 4 output rows: exp(-a*|d - d_tap0|), tap0 = (-1,-1) ----
    for (int i = tid; i < 4 * 9 * TPX; i += 512) {
        int p  = i & 63;
        int t  = i >> 6;                                // 0..35
        int yy = t / 9, tap = t - yy * 9;
        int ri = tap / 3, dj = tap - ri * 3;
        float dt = s_d[yy + ri][p + dj];
        float dc = s_d[yy][p];
        s_sim[yy][tap][p] = __expf(-ALPHA * fabsf(dt - dc));
    }

    float bias_v[4];
    #pragma unroll
    for (int r = 0; r < 4; ++r) bias_v[r] = bias[o_base + lq * 4 + r];

    __syncthreads();

    // ---- compute this wave's y-pair; A-frags JIT-loaded per (r,dj) ----
    f32x4 a0[4], a1[4];
    #pragma unroll
    for (int nt = 0; nt < 4; ++nt) {
        a0[nt] = f32x4{0.f, 0.f, 0.f, 0.f};
        a1[nt] = f32x4{0.f, 0.f, 0.f, 0.f};
    }

    #pragma unroll 1
    for (int r = 0; r < 4; ++r) {
        const int rr = 2 * pr + r;
        #pragma unroll 1
        for (int dj = 0; dj < 3; ++dj) {
            const int t0 = 3 * r + dj;             // tap for row y0+2pr   (r<3)
            const int t1 = 3 * (r - 1) + dj;       // tap for row y0+2pr+1 (r>=1)
            short8 wA00, wA01, wA10, wA11;
            if (r < 3) {
                wA00 = *(const short8*)&wt[(t0 * 64 + o_base + l15) * 64 + lq * 8];
                wA01 = *(const short8*)&wt[(t0 * 64 + o_base + l15) * 64 + 32 + lq * 8];
            }
            if (r >= 1) {
                wA10 = *(const short8*)&wt[(t1 * 64 + o_base + l15) * 64 + lq * 8];
                wA11 = *(const short8*)&wt[(t1 * 64 + o_base + l15) * 64 + 32 + lq * 8];
            }
            #pragma unroll
            for (int nt = 0; nt < 4; ++nt) {
                const int xb = nt * 16 + l15;
                short8 b0 = *(const short8*)&s_img[img_idx(rr, xb + dj, lq * 8)];
                short8 b1 = *(const short8*)&s_img[img_idx(rr, xb + dj, 32 + lq * 8)];
                if (r < 3) {
                    f32x4 t = __builtin_amdgcn_mfma_f32_16x16x32_bf16(
                        wA00, b0, (f32x4){0.f, 0.f, 0.f, 0.f}, 0, 0, 0);
                    t = __builtin_amdgcn_mfma_f32_16x16x32_bf16(wA01, b1, t, 0, 0, 0);
                    const float sv = s_sim[2 * pr][t0][xb];
                    #pragma unroll
                    for (int e = 0; e < 4; ++e) a0[nt][e] = fmaf(sv, t[e], a0[nt][e]);
                }
                if (r >= 1) {
                    f32x4 t = __builtin_amdgcn_mfma_f32_16x16x32_bf16(
                        wA10, b0, (f32x4){0.f, 0.f, 0.f, 0.f}, 0, 0, 0);
                    t = __builtin_amdgcn_mfma_f32_16x16x32_bf16(wA11, b1, t, 0, 0, 0);
                    const float sv = s_sim[2 * pr + 1][t1][xb];
                    #pragma unroll
                    for (int e = 0; e < 4; ++e) a1[nt][e] = fmaf(sv, t[e], a1[nt][e]);
                }
            }
        }
    }

    // ---- epilogue: bias + store ----
    const int yb = y0 + 2 * pr;
    #pragma unroll
    for (int nt = 0; nt < 4; ++nt) {
        const int px = x0 + nt * 16 + l15;
        #pragma unroll
        for (int rr = 0; rr < 4; ++rr) {
            const int o = o_base + lq * 4 + rr;
            out[((b * COUT + o) * HH + yb) * WW + px]     = a0[nt][rr] + bias_v[rr];
            out[((b * COUT + o) * HH + yb + 1) * WW + px] = a1[nt][rr] + bias_v[rr];
        }
    }
}

extern "C" void kernel_launch(void* const* d_in, const int* in_sizes, int n_in,
                              void* d_out, int out_size, void* d_ws, size_t ws_size,
                              hipStream_t stream) {
    const float* image  = (const float*)d_in[0];
    const float* depth  = (const float*)d_in[1];
    const float* weight = (const float*)d_in[2];
    const float* bias   = (const float*)d_in[3];
    float* out = (float*)d_out;
    __hip_bfloat16* wt = (__hip_bfloat16*)d_ws;       // 9*64*64 bf16 = 73728 B

    transpose_w<<<(9 * 64 * 64 + 255) / 256, 256, 0, stream>>>(weight, wt);

    dim3 grid(BATCH * 2 * 32);                        // 512 blocks, 4 y-rows each
    depthconv_fused<<<grid, 512, 0, stream>>>(image, depth, bias,
                                              (const short*)wt, out);
}